// Round 13
// baseline (2842.758 us; speedup 1.0000x reference)
//
#include <hip/hip_runtime.h>
#include <hip/hip_bf16.h>

#define NCLS 3
#define NPTS 64
#define NEDGE 2016   // 64*63/2
#define MIN_SAMP 200
#define PENDCAP 128

__device__ int          g_counts[NCLS];
__device__ int          g_sel[NCLS][NPTS];
__device__ float        g_Dm[NCLS][NPTS * NPTS];
__device__ float        g_tp[NCLS];
__device__ int          g_ovf[NCLS];
__device__ unsigned int g_rows[NCLS][NEDGE][64];   // fallback-only state

__global__ void init_k() {
    if (threadIdx.x < NCLS) { g_counts[threadIdx.x] = 0; g_ovf[threadIdx.x] = 0; }
}

__global__ __launch_bounds__(256) void count_k(const int* __restrict__ labels, int N) {
    __shared__ int c3[NCLS];
    if (threadIdx.x < NCLS) c3[threadIdx.x] = 0;
    __syncthreads();
    for (int i = blockIdx.x * blockDim.x + threadIdx.x; i < N; i += gridDim.x * blockDim.x) {
        int c = labels[i];
        if ((unsigned)c < NCLS) atomicAdd(&c3[c], 1);
    }
    __syncthreads();
    if (threadIdx.x < NCLS) atomicAdd(&g_counts[threadIdx.x], c3[threadIdx.x]);
}

__global__ __launch_bounds__(64) void select_k(const int* __restrict__ labels, int N) {
    const int lane = threadIdx.x;
    int cnt[NCLS] = {0, 0, 0};
    for (int base = 0; base < N; base += 64) {
        if (cnt[0] >= NPTS && cnt[1] >= NPTS && cnt[2] >= NPTS) break;
        int lab = (base + lane < N) ? labels[base + lane] : -1;
        for (int c = 0; c < NCLS; ++c) {
            if (cnt[c] >= NPTS) continue;
            unsigned long long m = __ballot(lab == c);
            if (!m) continue;
            int pos = cnt[c] + __popcll(m & ((1ull << lane) - 1ull));
            if (lab == c && pos < NPTS) g_sel[c][pos] = base + lane;
            cnt[c] = min(NPTS, cnt[c] + (int)__popcll(m));
        }
    }
}

__global__ __launch_bounds__(256) void dist_k(const float* __restrict__ feat) {
    int cls = blockIdx.x;
    if (g_counts[cls] < MIN_SAMP) return;
    int p = blockIdx.y * 256 + threadIdx.x;
    int i = p >> 6, j = p & 63;
    const float4* pi = (const float4*)(feat + (size_t)g_sel[cls][i] * 768);
    const float4* pj = (const float4*)(feat + (size_t)g_sel[cls][j] * 768);
    float sq = 0.f;
    #pragma unroll 4
    for (int d = 0; d < 192; ++d) {
        float4 va = pi[d], vb = pj[d];
        float dx = va.x - vb.x, dy = va.y - vb.y, dz = va.z - vb.z, dw = va.w - vb.w;
        sq = fmaf(dx, dx, sq); sq = fmaf(dy, dy, sq);
        sq = fmaf(dz, dz, sq); sq = fmaf(dw, dw, sq);
    }
    g_Dm[cls][p] = sqrtf(fmaxf(sq, 1e-12f));
}

__device__ __forceinline__ uint4 shfl4(uint4 v, int src) {
    uint4 r;
    r.x = (unsigned)__shfl((int)v.x, src);
    r.y = (unsigned)__shfl((int)v.y, src);
    r.z = (unsigned)__shfl((int)v.z, src);
    r.w = (unsigned)__shfl((int)v.w, src);
    return r;
}
__device__ __forceinline__ void xor4(uint4& a, const uint4 b) {
    a.x ^= b.x; a.y ^= b.y; a.z ^= b.z; a.w ^= b.w;
}
__device__ __forceinline__ unsigned int getw4(const uint4 a, int m) {
    return (m < 32) ? a.x : (m < 64) ? a.y : (m < 96) ? a.z : a.w;
}
__device__ __forceinline__ void set4(uint4& a, int m) {
    const unsigned int b = 1u << (m & 31);
    if (m < 32) a.x |= b; else if (m < 64) a.y |= b; else if (m < 96) a.z |= b; else a.w |= b;
}

// apply mutually-reduced pending updates to v (order-free; see theory)
__device__ __forceinline__ uint4 pend_apply(uint4 v, const uint4 pm,
                                            const uint4* s_pend, const unsigned char* s_pidx) {
    unsigned int w;
    w = v.x & pm.x;
    while (w) { int c = __builtin_ctz(w); w &= w - 1; xor4(v, s_pend[s_pidx[c]]); }
    w = v.y & pm.y;
    while (w) { int c = __builtin_ctz(w); w &= w - 1; xor4(v, s_pend[s_pidx[32 + c]]); }
    w = v.z & pm.z;
    while (w) { int c = __builtin_ctz(w); w &= w - 1; xor4(v, s_pend[s_pidx[64 + c]]); }
    w = v.w & pm.w;
    while (w) { int c = __builtin_ctz(w); w &= w - 1; xor4(v, s_pend[s_pidx[96 + c]]); }
    return v;
}

// ---------------- fast path: annotation H1 persistence, lazy batched updates ----------------
// Identical to the R7/R12 champion EXCEPT: the per-lane vertex potential `pi`
// is deleted. Proof it was dead: pi starts 0 and its only mutation was
// pend_apply(pi,...) in the flush, which maps 0 -> 0 (w = 0 & pm = 0). Hence
// ann = shfl4(pi,i)^shfl4(pi,j) always computed 0 via 8 ds_bpermute ops per
// group. Tree-edge annotations are identically 0 in this scheme; ann is now
// a register: 0 for negative edges, the fresh slot bit for positive edges.
__global__ __launch_bounds__(1024) void persist_fast_k() {
    const int cls  = blockIdx.x;
    const int tid  = threadIdx.x;
    const int lane = tid & 63;
    const int wid  = tid >> 6;
    if (g_counts[cls] < MIN_SAMP) return;

    __shared__ union UA {
        float sDm[NPTS * NPTS];          // ranking phase (16 KB)
        uint4 M[NEDGE];                  // edge annotations (32.25 KB)
    } uA;
    __shared__ short         rank2d[NPTS * NPTS];       // 8 KB
    __shared__ unsigned char se_i[NEDGE], se_j[NEDGE];  // 4 KB
    __shared__ float         ev[NEDGE];                 // 8 KB
    __shared__ unsigned char e2i[NEDGE], e2j[NEDGE];    // 4 KB (ranking only)
    __shared__ uint4         s_pend[PENDCAP];           // 2 KB
    __shared__ unsigned char s_pidx[128];

    for (int p = tid; p < NPTS * NPTS; p += 1024) uA.sDm[p] = g_Dm[cls][p];
    if (tid < NPTS - 1) {
        int i = tid;
        int base = i * (2 * NPTS - 1 - i) / 2;
        for (int j = i + 1; j < NPTS; ++j) {
            e2i[base + j - i - 1] = (unsigned char)i;
            e2j[base + j - i - 1] = (unsigned char)j;
        }
    }
    if (tid < NPTS) rank2d[tid * NPTS + tid] = 0x7fff;   // diagonal guard
    __syncthreads();

    // Rank edges by (value, i, j) — matches reference lexsort((jj,ii,vals)).
    for (int e = tid; e < NEDGE; e += 1024) {
        int i_ = e2i[e], j_ = e2j[e];
        float v = uA.sDm[i_ * NPTS + j_];
        int rk = 0;
        for (int f = 0; f < NEDGE; ++f) {
            int fi = e2i[f], fj = e2j[f];
            float w = uA.sDm[fi * NPTS + fj];
            bool less = (w < v) || (w == v && (fi < i_ || (fi == i_ && fj < j_)));
            rk += less ? 1 : 0;
        }
        se_i[rk] = (unsigned char)i_;
        se_j[rk] = (unsigned char)j_;
        ev[rk]   = v;
        rank2d[i_ * NPTS + j_] = (short)rk;
        rank2d[j_ * NPTS + i_] = (short)rk;
    }
    __syncthreads();          // ranking done; sDm dead, M takes over (no init needed)

    if (wid != 0) return;     // ---- single-wave main loop ----

    int   rootv = lane;                               // DSU root of vertex==lane
    uint4 occ      = make_uint4(0u, 0u, 0u, 0u);      // uniform across lanes
    uint4 pendmask = make_uint4(0u, 0u, 0u, 0u);
    int   pcount = 0, inuse = 0, bail = 0;
    double birth = 0.0, death = 0.0;

    for (int r = 0; r < NEDGE; ++r) {
        // ---- flush pending when list or slot pressure is high ----
        if (pcount >= 64 || inuse >= 126) {
            for (int x = lane; x < r; x += 64) {
                uint4 row = uA.M[x];
                const unsigned int anyw = (row.x & pendmask.x) | (row.y & pendmask.y)
                                        | (row.z & pendmask.z) | (row.w & pendmask.w);
                if (anyw) uA.M[x] = pend_apply(row, pendmask, s_pend, s_pidx);
            }
            occ.x &= ~pendmask.x; occ.y &= ~pendmask.y;
            occ.z &= ~pendmask.z; occ.w &= ~pendmask.w;
            inuse -= pcount; pcount = 0;
            pendmask = make_uint4(0u, 0u, 0u, 0u);
            if (inuse >= 127) { bail = 1; break; }   // genuine beta_1 overflow
        }

        const int i_ = se_i[r], j_ = se_j[r];
        const float evr = ev[r];

        // ---- edge event, fully uniform & registerized (tree annotations == 0) ----
        const int rootI = __shfl(rootv, i_);
        const int rootJ = __shfl(rootv, j_);
        uint4 ann = make_uint4(0u, 0u, 0u, 0u);
        if (rootI != rootJ) {
            rootv = (rootv == rootI) ? rootJ : rootv;    // merge (full compression kept)
        } else {
            birth += (double)evr;                        // positive edge: new class
            int s = (~occ.x) ? __builtin_ctz(~occ.x)
                  : (~occ.y) ? 32 + __builtin_ctz(~occ.y)
                  : (~occ.z) ? 64 + __builtin_ctz(~occ.z)
                  : (~occ.w) ? 96 + __builtin_ctz(~occ.w) : -1;
            if (s < 0) { bail = 1; break; }
            set4(occ, s); ++inuse;
            set4(ann, s);
        }
        if (lane == 0) uA.M[r] = ann;                    // stored stale-basis; ann reused below

        // ---- candidate triangles of this group ----
        const int a_l = rank2d[i_ * NPTS + lane];
        const int b_l = rank2d[j_ * NPTS + lane];
        const bool validk = (lane != i_) && (lane != j_) && (a_l < r) && (b_l < r);
        if (!__ballot(validk)) continue;

        uint4 v = make_uint4(0u, 0u, 0u, 0u);
        if (validk) {
            v = uA.M[a_l];
            xor4(v, uA.M[b_l]);
            xor4(v, ann);
            v = pend_apply(v, pendmask, s_pend, s_pidx); // bring to current basis
        }

        // ---- wave-synchronous Gauss-Jordan over valid lanes ----
        uint4 s4 = make_uint4(0u, 0u, 0u, 0u);
        int accidx = -1, accm = 0;
        int d = 0;
        while (true) {
            unsigned long long nzm = __ballot((v.x | v.y | v.z | v.w) != 0u);
            if (!nzm) break;
            const int l = __builtin_ctzll(nzm);
            const uint4 p = shfl4(v, l);
            const int m = p.x ? __builtin_ctz(p.x) : p.y ? 32 + __builtin_ctz(p.y)
                       : p.z ? 64 + __builtin_ctz(p.z) : 96 + __builtin_ctz(p.w);
            if (lane == l) { s4 = v; accidx = d; accm = m; }
            const unsigned int mb2 = 1u << (m & 31);
            if (getw4(v, m) & mb2) xor4(v, p);
            if (accidx >= 0 && accidx < d) {
                if (getw4(s4, m) & mb2) xor4(s4, p);
            }
            ++d;
        }
        if (d == 0) continue;
        death += (double)d * (double)evr;

        // ---- append new pending updates (mutually-reduced form) ----
        const int pbase = pcount;
        if (accidx >= 0) {
            s_pend[pbase + accidx] = s4;
            s_pidx[accm] = (unsigned char)(pbase + accidx);
        }
        for (int t = 0; t < d; ++t) {
            const unsigned long long who = __ballot(accidx == t);
            const int l = __builtin_ctzll(who);
            const int m = __shfl(accm, l);
            const uint4 u4 = shfl4(s4, l);
            set4(pendmask, m);
            const unsigned int mb2 = 1u << (m & 31);
            for (int x = lane; x < pbase; x += 64) {     // keep old pending reduced vs new pivot
                uint4 q = s_pend[x];
                if (getw4(q, m) & mb2) { xor4(q, u4); s_pend[x] = q; }
            }
        }
        pcount += d;
    }

    if (lane == 0) {
        if (bail) g_ovf[cls] = 1;
        else      g_tp[cls] = (float)(death - birth);
    }
}

// ---------------- fallback: R3's validated exact Row-matrix reduction ----------------
__global__ __launch_bounds__(1024) void persist_exact_k() {
    const int cls  = blockIdx.x;
    const int tid  = threadIdx.x;
    const int lane = tid & 63;
    const int wid  = tid >> 6;
    if (g_counts[cls] < MIN_SAMP) return;
    if (!g_ovf[cls]) return;

    union PhaseU {
        float        sDm[NPTS * NPTS];
        unsigned int pbuf[62][64];
    };
    __shared__ PhaseU        u;
    __shared__ short         rank2d[NPTS * NPTS];
    __shared__ unsigned char e2i[NEDGE], e2j[NEDGE];
    __shared__ unsigned char se_i[NEDGE], se_j[NEDGE];
    __shared__ float         ev[NEDGE];
    __shared__ unsigned char cstate[64];
    __shared__ int           s_t;
    __shared__ double        s_birth, s_death;
    __shared__ unsigned char parent[NPTS];

    for (int p = tid; p < NPTS * NPTS; p += 1024) u.sDm[p] = g_Dm[cls][p];
    if (tid < NPTS - 1) {
        int i = tid;
        int base = i * (2 * NPTS - 1 - i) / 2;
        for (int j = i + 1; j < NPTS; ++j) {
            e2i[base + j - i - 1] = (unsigned char)i;
            e2j[base + j - i - 1] = (unsigned char)j;
        }
    }
    for (int x = tid; x < NEDGE * 64; x += 1024) {
        int rr = x >> 6, w = x & 63;
        g_rows[cls][rr][w] = (w == (rr >> 5)) ? (1u << (rr & 31)) : 0u;
    }
    if (tid < NPTS) rank2d[tid * NPTS + tid] = 0x7fff;
    __syncthreads();

    for (int e = tid; e < NEDGE; e += 1024) {
        int i_ = e2i[e], j_ = e2j[e];
        float v = u.sDm[i_ * NPTS + j_];
        int rk = 0;
        for (int f = 0; f < NEDGE; ++f) {
            int fi = e2i[f], fj = e2j[f];
            float w = u.sDm[fi * NPTS + fj];
            bool less = (w < v) || (w == v && (fi < i_ || (fi == i_ && fj < j_)));
            rk += less ? 1 : 0;
        }
        se_i[rk] = (unsigned char)i_;
        se_j[rk] = (unsigned char)j_;
        ev[rk]   = v;
        rank2d[i_ * NPTS + j_] = (short)rk;
        rank2d[j_ * NPTS + i_] = (short)rk;
    }
    __syncthreads();

    if (tid == 0) {
        for (int i = 0; i < NPTS; ++i) parent[i] = (unsigned char)i;
        double bs = 0.0;
        for (int r = 0; r < NEDGE; ++r) {
            int x = se_i[r]; while (parent[x] != x) { parent[x] = parent[parent[x]]; x = parent[x]; }
            int y = se_j[r]; while (parent[y] != y) { parent[y] = parent[parent[y]]; y = parent[y]; }
            if (x == y) bs += (double)ev[r];
            else parent[x] = (unsigned char)y;
        }
        s_birth = bs; s_death = 0.0;
    }
    __syncthreads();

    unsigned int (*Row)[64] = g_rows[cls];

    for (int r = 1; r < NEDGE; ++r) {
        const int i_ = se_i[r], j_ = se_j[r];
        const int a_l = rank2d[i_ * NPTS + lane];
        const int b_l = rank2d[j_ * NPTS + lane];
        const bool valid = (lane != i_) && (lane != j_) && (a_l < r) && (b_l < r);
        const unsigned long long mask = __ballot(valid);
        if (!mask) continue;
        const int cnt = __popcll(mask);

        {
            const unsigned int rrow = Row[r][lane];
            for (int idx = wid; idx < cnt; idx += 16) {
                unsigned long long mm = mask;
                for (int s = 0; s < idx; ++s) mm &= mm - 1;
                const int k = __builtin_ctzll(mm);
                const int a = __shfl(a_l, k);
                const int b = __shfl(b_l, k);
                const unsigned int p = Row[a][lane] ^ Row[b][lane] ^ rrow;
                u.pbuf[idx][lane] = p;
                const bool indep = (__ballot(p != 0u) != 0ull);
                if (lane == 0) cstate[idx] = indep ? 1 : 0;
            }
        }
        __syncthreads();

        while (true) {
            int c = -1;
            for (int x = 0; x < cnt; ++x) if (cstate[x] == 1) { c = x; break; }
            if (c < 0) break;
            __syncthreads();
            if (wid == 0) {
                const unsigned int pw = u.pbuf[c][lane];
                const unsigned long long m2 = __ballot(pw != 0u);
                const int fl = __builtin_ctzll(m2);
                const unsigned int w0 = (unsigned int)__shfl((int)pw, fl);
                if (lane == 0) s_t = fl * 32 + __builtin_ctz(w0);
            }
            if (tid == 0) { s_death += (double)ev[r]; cstate[c] = 2; }
            __syncthreads();
            const int t = s_t, tw = t >> 5;
            const unsigned int tb = 1u << (t & 31);
            const unsigned int pw = u.pbuf[c][lane];
            for (int rr0 = wid * 64; rr0 < NEDGE; rr0 += 1024) {
                const int rr = rr0 + lane;
                unsigned int hit = (rr < NEDGE) ? (Row[rr][tw] & tb) : 0u;
                unsigned long long mrows = __ballot(hit != 0u);
                while (mrows) {
                    const int rx = rr0 + __builtin_ctzll(mrows);
                    mrows &= mrows - 1;
                    Row[rx][lane] ^= pw;
                }
            }
            __threadfence_block();
            __syncthreads();
            {
                const unsigned int rrow2 = Row[r][lane];
                for (int idx = wid; idx < cnt; idx += 16) {
                    if (cstate[idx] != 1) continue;
                    unsigned long long mm = mask;
                    for (int s = 0; s < idx; ++s) mm &= mm - 1;
                    const int k = __builtin_ctzll(mm);
                    const int a = __shfl(a_l, k);
                    const int b = __shfl(b_l, k);
                    const unsigned int p2 = Row[a][lane] ^ Row[b][lane] ^ rrow2;
                    u.pbuf[idx][lane] = p2;
                    const bool indep = (__ballot(p2 != 0u) != 0ull);
                    if (lane == 0) cstate[idx] = indep ? 1 : 0;
                }
            }
            __syncthreads();
        }
        __syncthreads();
    }

    if (tid == 0) g_tp[cls] = (float)(s_death - s_birth);
}

__global__ void final_k(const float* __restrict__ tgt, float* __restrict__ out) {
    double total = 0.0;
    int valid = 0;
    for (int c = 0; c < NCLS; ++c) {
        if (g_counts[c] >= MIN_SAMP) {
            double tpt = 0.0;
            for (int p = 0; p < 100; ++p)
                tpt += (double)tgt[(c * 100 + p) * 2 + 1] - (double)tgt[(c * 100 + p) * 2 + 0];
            double d = (double)g_tp[c] - tpt;
            total += d * d;
            valid++;
        }
    }
    *out = valid ? (float)(total / valid) : 0.0f;
}

extern "C" void kernel_launch(void* const* d_in, const int* in_sizes, int n_in,
                              void* d_out, int out_size, void* d_ws, size_t ws_size,
                              hipStream_t stream) {
    const float* feat   = (const float*)d_in[0];
    const int*   labels = (const int*)d_in[1];
    const float* tgt    = (const float*)d_in[2];
    const int N = in_sizes[1];

    hipLaunchKernelGGL(init_k,         dim3(1),        dim3(64),   0, stream);
    hipLaunchKernelGGL(count_k,        dim3(256),      dim3(256),  0, stream, labels, N);
    hipLaunchKernelGGL(select_k,       dim3(1),        dim3(64),   0, stream, labels, N);
    hipLaunchKernelGGL(dist_k,         dim3(NCLS, 16), dim3(256),  0, stream, feat);
    hipLaunchKernelGGL(persist_fast_k, dim3(NCLS),     dim3(1024), 0, stream);
    hipLaunchKernelGGL(persist_exact_k,dim3(NCLS),     dim3(1024), 0, stream);
    hipLaunchKernelGGL(final_k,        dim3(1),        dim3(1),    0, stream, tgt, (float*)d_out);
}

// Round 14
// 2376.059 us; speedup vs baseline: 1.1964x; 1.1964x over previous
//
#include <hip/hip_runtime.h>
#include <hip/hip_bf16.h>

#define NCLS 3
#define NPTS 64
#define NEDGE 2016   // 64*63/2 = 126 * 16
#define MIN_SAMP 200
#define PENDCAP 128
#define BLK 16
#define MAXCAND (BLK * 62)   // 992

__device__ int          g_counts[NCLS];
__device__ int          g_sel[NCLS][NPTS];
__device__ float        g_Dm[NCLS][NPTS * NPTS];
__device__ float        g_tp[NCLS];
__device__ int          g_ovf[NCLS];
__device__ unsigned int g_rows[NCLS][NEDGE][64];   // fallback-only state

__global__ void init_k() {
    if (threadIdx.x < NCLS) { g_counts[threadIdx.x] = 0; g_ovf[threadIdx.x] = 0; }
}

__global__ __launch_bounds__(256) void count_k(const int* __restrict__ labels, int N) {
    __shared__ int c3[NCLS];
    if (threadIdx.x < NCLS) c3[threadIdx.x] = 0;
    __syncthreads();
    for (int i = blockIdx.x * blockDim.x + threadIdx.x; i < N; i += gridDim.x * blockDim.x) {
        int c = labels[i];
        if ((unsigned)c < NCLS) atomicAdd(&c3[c], 1);
    }
    __syncthreads();
    if (threadIdx.x < NCLS) atomicAdd(&g_counts[threadIdx.x], c3[threadIdx.x]);
}

__global__ __launch_bounds__(64) void select_k(const int* __restrict__ labels, int N) {
    const int lane = threadIdx.x;
    int cnt[NCLS] = {0, 0, 0};
    for (int base = 0; base < N; base += 64) {
        if (cnt[0] >= NPTS && cnt[1] >= NPTS && cnt[2] >= NPTS) break;
        int lab = (base + lane < N) ? labels[base + lane] : -1;
        for (int c = 0; c < NCLS; ++c) {
            if (cnt[c] >= NPTS) continue;
            unsigned long long m = __ballot(lab == c);
            if (!m) continue;
            int pos = cnt[c] + __popcll(m & ((1ull << lane) - 1ull));
            if (lab == c && pos < NPTS) g_sel[c][pos] = base + lane;
            cnt[c] = min(NPTS, cnt[c] + (int)__popcll(m));
        }
    }
}

__global__ __launch_bounds__(256) void dist_k(const float* __restrict__ feat) {
    int cls = blockIdx.x;
    if (g_counts[cls] < MIN_SAMP) return;
    int p = blockIdx.y * 256 + threadIdx.x;
    int i = p >> 6, j = p & 63;
    const float4* pi = (const float4*)(feat + (size_t)g_sel[cls][i] * 768);
    const float4* pj = (const float4*)(feat + (size_t)g_sel[cls][j] * 768);
    float sq = 0.f;
    #pragma unroll 4
    for (int d = 0; d < 192; ++d) {
        float4 va = pi[d], vb = pj[d];
        float dx = va.x - vb.x, dy = va.y - vb.y, dz = va.z - vb.z, dw = va.w - vb.w;
        sq = fmaf(dx, dx, sq); sq = fmaf(dy, dy, sq);
        sq = fmaf(dz, dz, sq); sq = fmaf(dw, dw, sq);
    }
    g_Dm[cls][p] = sqrtf(fmaxf(sq, 1e-12f));
}

__device__ __forceinline__ uint4 shfl4(uint4 v, int src) {
    uint4 r;
    r.x = (unsigned)__shfl((int)v.x, src);
    r.y = (unsigned)__shfl((int)v.y, src);
    r.z = (unsigned)__shfl((int)v.z, src);
    r.w = (unsigned)__shfl((int)v.w, src);
    return r;
}
__device__ __forceinline__ void xor4(uint4& a, const uint4 b) {
    a.x ^= b.x; a.y ^= b.y; a.z ^= b.z; a.w ^= b.w;
}
__device__ __forceinline__ unsigned int getw4(const uint4 a, int m) {
    return (m < 32) ? a.x : (m < 64) ? a.y : (m < 96) ? a.z : a.w;
}
__device__ __forceinline__ void set4(uint4& a, int m) {
    const unsigned int b = 1u << (m & 31);
    if (m < 32) a.x |= b; else if (m < 64) a.y |= b; else if (m < 96) a.z |= b; else a.w |= b;
}

// apply mutually-reduced pending updates to v (order-free; validated R7)
__device__ __forceinline__ uint4 pend_apply(uint4 v, const uint4 pm,
                                            const uint4* s_pend, const unsigned char* s_pidx) {
    unsigned int w;
    w = v.x & pm.x;
    while (w) { int c = __builtin_ctz(w); w &= w - 1; xor4(v, s_pend[s_pidx[c]]); }
    w = v.y & pm.y;
    while (w) { int c = __builtin_ctz(w); w &= w - 1; xor4(v, s_pend[s_pidx[32 + c]]); }
    w = v.z & pm.z;
    while (w) { int c = __builtin_ctz(w); w &= w - 1; xor4(v, s_pend[s_pidx[64 + c]]); }
    w = v.w & pm.w;
    while (w) { int c = __builtin_ctz(w); w &= w - 1; xor4(v, s_pend[s_pidx[96 + c]]); }
    return v;
}

// ---------------- fast path: blocked annotation H1 persistence ----------------
// 126 blocks of 16 edge-groups. Per block, all 16 waves in lockstep:
//   events: redundantly uniform on all waves (shfl DSU + slot alloc); wave-0
//           lanes write the 16 M rows.
//   tests:  wave w computes group (r+w)'s candidate vectors vs block-start
//           basis (stale M + pend_apply), compacted group-major into vbuf.
//   GJ:     wave 0 reduces chunks of 64 candidates in filtration order
//           (earlier chunks' pivots applied via npmB; in-chunk order = lane
//           order); appends to the mutually-reduced pending list (R7 scheme).
// Exactness: candidate at group g sees block-start pending (helpers) +
// in-block deaths from groups < g (npmB or GJ elimination order) = sequential.
__global__ __launch_bounds__(1024) void persist_fast_k() {
    const int cls  = blockIdx.x;
    const int tid  = threadIdx.x;
    const int lane = tid & 63;
    const int wid  = tid >> 6;
    if (g_counts[cls] < MIN_SAMP) return;

    __shared__ union UA {
        float sDm[NPTS * NPTS];          // ranking phase (16 KB)
        uint4 M[NEDGE];                  // edge annotations (32.25 KB)
    } uA;
    __shared__ short         rank2d[NPTS * NPTS];       // 8 KB
    __shared__ unsigned char se_i[NEDGE], se_j[NEDGE];  // 4 KB
    __shared__ float         ev[NEDGE];                 // 8 KB
    __shared__ unsigned char e2i[NEDGE], e2j[NEDGE];    // 4 KB (ranking only)
    __shared__ uint4         s_pend[PENDCAP];           // 2 KB
    __shared__ unsigned char s_pidx[128];
    __shared__ uint4         vbuf[MAXCAND];             // 15.5 KB
    __shared__ unsigned char gidb[MAXCAND];             // 1 KB
    __shared__ int           s_cnt[BLK];
    __shared__ uint4         s_npm;
    __shared__ int           s_d, s_ovf;

    for (int p = tid; p < NPTS * NPTS; p += 1024) uA.sDm[p] = g_Dm[cls][p];
    if (tid < NPTS - 1) {
        int i = tid;
        int base = i * (2 * NPTS - 1 - i) / 2;
        for (int j = i + 1; j < NPTS; ++j) {
            e2i[base + j - i - 1] = (unsigned char)i;
            e2j[base + j - i - 1] = (unsigned char)j;
        }
    }
    if (tid < NPTS) rank2d[tid * NPTS + tid] = 0x7fff;   // diagonal guard
    __syncthreads();

    // Rank edges by (value, i, j) — matches reference lexsort((jj,ii,vals)).
    for (int e = tid; e < NEDGE; e += 1024) {
        int i_ = e2i[e], j_ = e2j[e];
        float v = uA.sDm[i_ * NPTS + j_];
        int rk = 0;
        for (int f = 0; f < NEDGE; ++f) {
            int fi = e2i[f], fj = e2j[f];
            float w = uA.sDm[fi * NPTS + fj];
            bool less = (w < v) || (w == v && (fi < i_ || (fi == i_ && fj < j_)));
            rk += less ? 1 : 0;
        }
        se_i[rk] = (unsigned char)i_;
        se_j[rk] = (unsigned char)j_;
        ev[rk]   = v;
        rank2d[i_ * NPTS + j_] = (short)rk;
        rank2d[j_ * NPTS + i_] = (short)rk;
    }
    __syncthreads();          // ranking done; sDm dead, M takes over

    // ---- uniform state, maintained identically on ALL waves ----
    int    rootv = lane;                               // DSU root of vertex==lane
    uint4  occ      = make_uint4(0u, 0u, 0u, 0u);
    uint4  pendmask = make_uint4(0u, 0u, 0u, 0u);
    int    pcount = 0, inuse = 0, bail = 0;
    double birth = 0.0, death = 0.0;                   // death used on wave 0 only

    for (int r = 0; r < NEDGE; r += BLK) {
        // ---- flush (uniform decision; all 1024 threads participate) ----
        if (pcount >= 48 || inuse >= 110) {
            for (int x = tid; x < r; x += 1024) {
                uint4 row = uA.M[x];
                const unsigned int anyw = (row.x & pendmask.x) | (row.y & pendmask.y)
                                        | (row.z & pendmask.z) | (row.w & pendmask.w);
                if (anyw) uA.M[x] = pend_apply(row, pendmask, s_pend, s_pidx);
            }
            occ.x &= ~pendmask.x; occ.y &= ~pendmask.y;
            occ.z &= ~pendmask.z; occ.w &= ~pendmask.w;
            inuse -= pcount; pcount = 0;
            pendmask = make_uint4(0u, 0u, 0u, 0u);
            __syncthreads();                           // flushed M visible
            if (inuse >= 110) { bail = 1; break; }     // genuine overflow (uniform)
        }

        // ---- events: redundantly uniform on all waves ----
        for (int t = 0; t < BLK; ++t) {
            const int g = r + t;
            const int i_ = se_i[g], j_ = se_j[g];
            const int rootI = __shfl(rootv, i_);
            const int rootJ = __shfl(rootv, j_);
            uint4 ann = make_uint4(0u, 0u, 0u, 0u);
            if (rootI != rootJ) {
                rootv = (rootv == rootI) ? rootJ : rootv;
            } else {
                birth += (double)ev[g];
                int s = (~occ.x) ? __builtin_ctz(~occ.x)
                      : (~occ.y) ? 32 + __builtin_ctz(~occ.y)
                      : (~occ.z) ? 64 + __builtin_ctz(~occ.z)
                      : (~occ.w) ? 96 + __builtin_ctz(~occ.w) : -1;
                if (s < 0) { bail = 1; }
                else { set4(occ, s); ++inuse; set4(ann, s); }
            }
            if (tid == t) uA.M[g] = ann;               // wave-0 lane t writes
        }
        if (bail) break;                               // uniform
        __syncthreads();                               // B1: M rows visible

        // ---- tests: wave w handles group r+w ----
        uint4 v = make_uint4(0u, 0u, 0u, 0u);
        unsigned long long mask;
        {
            const int g = r + wid;
            const int i_ = se_i[g], j_ = se_j[g];
            const short a_l = rank2d[i_ * NPTS + lane];
            const short b_l = rank2d[j_ * NPTS + lane];
            const bool valid = (lane != i_) && (lane != j_) && (a_l < g) && (b_l < g);
            mask = __ballot(valid);
            if (lane == 0) s_cnt[wid] = (int)__popcll(mask);
            if (valid) {
                v = uA.M[a_l];
                xor4(v, uA.M[b_l]);
                { uint4 t4 = uA.M[g]; xor4(v, t4); }
                v = pend_apply(v, pendmask, s_pend, s_pidx);   // block-start pending
            }
        }
        __syncthreads();                               // B2: s_cnt visible

        int base = 0, tot = 0;
        #pragma unroll
        for (int t2 = 0; t2 < BLK; ++t2) {
            const int c = s_cnt[t2];
            if (t2 < wid) base += c;
            tot += c;
        }
        if ((mask >> lane) & 1ull) {
            const int pos = base + (int)__popcll(mask & ((1ull << lane) - 1ull));
            vbuf[pos] = v;
            gidb[pos] = (unsigned char)wid;
        }
        __syncthreads();                               // B3: vbuf visible

        // ---- GJ + append: wave 0, chunks of 64 in filtration order ----
        if (wid == 0) {
            uint4 npmB = make_uint4(0u, 0u, 0u, 0u);
            int dB = 0, ovf = 0;
            for (int c0 = 0; c0 < tot; c0 += 64) {
                const int n = (tot - c0 < 64) ? (tot - c0) : 64;
                uint4 v2 = make_uint4(0u, 0u, 0u, 0u);
                float evl = 0.f;
                if (lane < n) {
                    v2 = vbuf[c0 + lane];
                    evl = ev[r + gidb[c0 + lane]];
                    v2 = pend_apply(v2, npmB, s_pend, s_pidx);   // earlier-chunk pivots
                }
                uint4 s4 = make_uint4(0u, 0u, 0u, 0u);
                int accidx = -1, accm = 0, d = 0;
                while (true) {
                    unsigned long long nzm = __ballot((v2.x | v2.y | v2.z | v2.w) != 0u);
                    if (!nzm) break;
                    const int l = __builtin_ctzll(nzm);
                    const uint4 p = shfl4(v2, l);
                    const float evp = __shfl(evl, l);
                    const int m = p.x ? __builtin_ctz(p.x) : p.y ? 32 + __builtin_ctz(p.y)
                               : p.z ? 64 + __builtin_ctz(p.z) : 96 + __builtin_ctz(p.w);
                    if (lane == l) { s4 = v2; accidx = d; accm = m; }
                    const unsigned int mb2 = 1u << (m & 31);
                    if (getw4(v2, m) & mb2) xor4(v2, p);
                    if (accidx >= 0 && accidx < d) {
                        if (getw4(s4, m) & mb2) xor4(s4, p);
                    }
                    death += (double)evp;
                    ++d;
                }
                if (d) {
                    const int pbase = pcount + dB;
                    if (pbase + d > PENDCAP) { ovf = 1; break; }
                    if (accidx >= 0) {
                        s_pend[pbase + accidx] = s4;
                        s_pidx[accm] = (unsigned char)(pbase + accidx);
                    }
                    for (int t3 = 0; t3 < d; ++t3) {
                        const unsigned long long who = __ballot(accidx == t3);
                        const int l = __builtin_ctzll(who);
                        const int m = __shfl(accm, l);
                        const uint4 u4 = shfl4(s4, l);
                        set4(npmB, m);
                        const unsigned int mb2 = 1u << (m & 31);
                        for (int x = lane; x < pbase; x += 64) {
                            uint4 q = s_pend[x];
                            if (getw4(q, m) & mb2) { xor4(q, u4); s_pend[x] = q; }
                        }
                    }
                    dB += d;
                }
            }
            if (lane == 0) { s_npm = npmB; s_d = dB; s_ovf = ovf; }
        }
        __syncthreads();                               // B4: broadcast
        {
            const uint4 npm = s_npm;
            pendmask.x |= npm.x; pendmask.y |= npm.y;
            pendmask.z |= npm.z; pendmask.w |= npm.w;
            pcount += s_d;
            if (s_ovf) { bail = 1; break; }            // uniform
        }
    }

    if (wid == 0 && lane == 0) {
        if (bail) g_ovf[cls] = 1;
        else      g_tp[cls] = (float)(death - birth);
    }
}

// ---------------- fallback: R3's validated exact Row-matrix reduction ----------------
__global__ __launch_bounds__(1024) void persist_exact_k() {
    const int cls  = blockIdx.x;
    const int tid  = threadIdx.x;
    const int lane = tid & 63;
    const int wid  = tid >> 6;
    if (g_counts[cls] < MIN_SAMP) return;
    if (!g_ovf[cls]) return;

    union PhaseU {
        float        sDm[NPTS * NPTS];
        unsigned int pbuf[62][64];
    };
    __shared__ PhaseU        u;
    __shared__ short         rank2d[NPTS * NPTS];
    __shared__ unsigned char e2i[NEDGE], e2j[NEDGE];
    __shared__ unsigned char se_i[NEDGE], se_j[NEDGE];
    __shared__ float         ev[NEDGE];
    __shared__ unsigned char cstate[64];
    __shared__ int           s_t;
    __shared__ double        s_birth, s_death;
    __shared__ unsigned char parent[NPTS];

    for (int p = tid; p < NPTS * NPTS; p += 1024) u.sDm[p] = g_Dm[cls][p];
    if (tid < NPTS - 1) {
        int i = tid;
        int base = i * (2 * NPTS - 1 - i) / 2;
        for (int j = i + 1; j < NPTS; ++j) {
            e2i[base + j - i - 1] = (unsigned char)i;
            e2j[base + j - i - 1] = (unsigned char)j;
        }
    }
    for (int x = tid; x < NEDGE * 64; x += 1024) {
        int rr = x >> 6, w = x & 63;
        g_rows[cls][rr][w] = (w == (rr >> 5)) ? (1u << (rr & 31)) : 0u;
    }
    if (tid < NPTS) rank2d[tid * NPTS + tid] = 0x7fff;
    __syncthreads();

    for (int e = tid; e < NEDGE; e += 1024) {
        int i_ = e2i[e], j_ = e2j[e];
        float v = u.sDm[i_ * NPTS + j_];
        int rk = 0;
        for (int f = 0; f < NEDGE; ++f) {
            int fi = e2i[f], fj = e2j[f];
            float w = u.sDm[fi * NPTS + fj];
            bool less = (w < v) || (w == v && (fi < i_ || (fi == i_ && fj < j_)));
            rk += less ? 1 : 0;
        }
        se_i[rk] = (unsigned char)i_;
        se_j[rk] = (unsigned char)j_;
        ev[rk]   = v;
        rank2d[i_ * NPTS + j_] = (short)rk;
        rank2d[j_ * NPTS + i_] = (short)rk;
    }
    __syncthreads();

    if (tid == 0) {
        for (int i = 0; i < NPTS; ++i) parent[i] = (unsigned char)i;
        double bs = 0.0;
        for (int r = 0; r < NEDGE; ++r) {
            int x = se_i[r]; while (parent[x] != x) { parent[x] = parent[parent[x]]; x = parent[x]; }
            int y = se_j[r]; while (parent[y] != y) { parent[y] = parent[parent[y]]; y = parent[y]; }
            if (x == y) bs += (double)ev[r];
            else parent[x] = (unsigned char)y;
        }
        s_birth = bs; s_death = 0.0;
    }
    __syncthreads();

    unsigned int (*Row)[64] = g_rows[cls];

    for (int r = 1; r < NEDGE; ++r) {
        const int i_ = se_i[r], j_ = se_j[r];
        const int a_l = rank2d[i_ * NPTS + lane];
        const int b_l = rank2d[j_ * NPTS + lane];
        const bool valid = (lane != i_) && (lane != j_) && (a_l < r) && (b_l < r);
        const unsigned long long mask = __ballot(valid);
        if (!mask) continue;
        const int cnt = __popcll(mask);

        {
            const unsigned int rrow = Row[r][lane];
            for (int idx = wid; idx < cnt; idx += 16) {
                unsigned long long mm = mask;
                for (int s = 0; s < idx; ++s) mm &= mm - 1;
                const int k = __builtin_ctzll(mm);
                const int a = __shfl(a_l, k);
                const int b = __shfl(b_l, k);
                const unsigned int p = Row[a][lane] ^ Row[b][lane] ^ rrow;
                u.pbuf[idx][lane] = p;
                const bool indep = (__ballot(p != 0u) != 0ull);
                if (lane == 0) cstate[idx] = indep ? 1 : 0;
            }
        }
        __syncthreads();

        while (true) {
            int c = -1;
            for (int x = 0; x < cnt; ++x) if (cstate[x] == 1) { c = x; break; }
            if (c < 0) break;
            __syncthreads();
            if (wid == 0) {
                const unsigned int pw = u.pbuf[c][lane];
                const unsigned long long m2 = __ballot(pw != 0u);
                const int fl = __builtin_ctzll(m2);
                const unsigned int w0 = (unsigned int)__shfl((int)pw, fl);
                if (lane == 0) s_t = fl * 32 + __builtin_ctz(w0);
            }
            if (tid == 0) { s_death += (double)ev[r]; cstate[c] = 2; }
            __syncthreads();
            const int t = s_t, tw = t >> 5;
            const unsigned int tb = 1u << (t & 31);
            const unsigned int pw = u.pbuf[c][lane];
            for (int rr0 = wid * 64; rr0 < NEDGE; rr0 += 1024) {
                const int rr = rr0 + lane;
                unsigned int hit = (rr < NEDGE) ? (Row[rr][tw] & tb) : 0u;
                unsigned long long mrows = __ballot(hit != 0u);
                while (mrows) {
                    const int rx = rr0 + __builtin_ctzll(mrows);
                    mrows &= mrows - 1;
                    Row[rx][lane] ^= pw;
                }
            }
            __threadfence_block();
            __syncthreads();
            {
                const unsigned int rrow2 = Row[r][lane];
                for (int idx = wid; idx < cnt; idx += 16) {
                    if (cstate[idx] != 1) continue;
                    unsigned long long mm = mask;
                    for (int s = 0; s < idx; ++s) mm &= mm - 1;
                    const int k = __builtin_ctzll(mm);
                    const int a = __shfl(a_l, k);
                    const int b = __shfl(b_l, k);
                    const unsigned int p2 = Row[a][lane] ^ Row[b][lane] ^ rrow2;
                    u.pbuf[idx][lane] = p2;
                    const bool indep = (__ballot(p2 != 0u) != 0ull);
                    if (lane == 0) cstate[idx] = indep ? 1 : 0;
                }
            }
            __syncthreads();
        }
        __syncthreads();
    }

    if (tid == 0) g_tp[cls] = (float)(s_death - s_birth);
}

__global__ void final_k(const float* __restrict__ tgt, float* __restrict__ out) {
    double total = 0.0;
    int valid = 0;
    for (int c = 0; c < NCLS; ++c) {
        if (g_counts[c] >= MIN_SAMP) {
            double tpt = 0.0;
            for (int p = 0; p < 100; ++p)
                tpt += (double)tgt[(c * 100 + p) * 2 + 1] - (double)tgt[(c * 100 + p) * 2 + 0];
            double d = (double)g_tp[c] - tpt;
            total += d * d;
            valid++;
        }
    }
    *out = valid ? (float)(total / valid) : 0.0f;
}

extern "C" void kernel_launch(void* const* d_in, const int* in_sizes, int n_in,
                              void* d_out, int out_size, void* d_ws, size_t ws_size,
                              hipStream_t stream) {
    const float* feat   = (const float*)d_in[0];
    const int*   labels = (const int*)d_in[1];
    const float* tgt    = (const float*)d_in[2];
    const int N = in_sizes[1];

    hipLaunchKernelGGL(init_k,         dim3(1),        dim3(64),   0, stream);
    hipLaunchKernelGGL(count_k,        dim3(256),      dim3(256),  0, stream, labels, N);
    hipLaunchKernelGGL(select_k,       dim3(1),        dim3(64),   0, stream, labels, N);
    hipLaunchKernelGGL(dist_k,         dim3(NCLS, 16), dim3(256),  0, stream, feat);
    hipLaunchKernelGGL(persist_fast_k, dim3(NCLS),     dim3(1024), 0, stream);
    hipLaunchKernelGGL(persist_exact_k,dim3(NCLS),     dim3(1024), 0, stream);
    hipLaunchKernelGGL(final_k,        dim3(1),        dim3(1),    0, stream, tgt, (float*)d_out);
}